// Round 3
// baseline (716.923 us; speedup 1.0000x reference)
//
#include <hip/hip_runtime.h>

#define HH 32
#define TT 512

typedef float v2f __attribute__((ext_vector_type(2)));

__device__ __forceinline__ v2f pk_fma(v2f a, v2f b, v2f c) {
    v2f d;
    asm("v_pk_fma_f32 %0, %1, %2, %3" : "=v"(d) : "v"(a), "v"(b), "v"(c));
    return d;
}
__device__ __forceinline__ v2f pk_mul(v2f a, v2f b) {
    v2f d;
    asm("v_pk_mul_f32 %0, %1, %2" : "=v"(d) : "v"(a), "v"(b));
    return d;
}
__device__ __forceinline__ v2f pk_add(v2f a, v2f b) {
    v2f d;
    asm("v_pk_add_f32 %0, %1, %2" : "=v"(d) : "v"(a), "v"(b));
    return d;
}
__device__ __forceinline__ v2f flo(float4 v) { return v2f{v.x, v.y}; }
__device__ __forceinline__ v2f fhi(float4 v) { return v2f{v.z, v.w}; }

__device__ __forceinline__ float fast_tanh(float z) {
    // tanh(z) = 1 - 2/(exp(2z)+1); exp2-based, ~1e-7 abs err (verified R1/R2)
    float e, r;
    float zz = z * 2.88539008177793f;  // 2*log2(e)
    asm("v_exp_f32 %0, %1" : "=v"(e) : "v"(zz));
    float d = e + 1.0f;
    asm("v_rcp_f32 %0, %1" : "=v"(r) : "v"(d));
    return __builtin_fmaf(-2.0f, r, 1.0f);
}

// Layer-split pipelined wave: one batch per 64-lane wave.
//   lanes 0..31  ("L1"): layer-1 row i, computing h1_t      at phase t
//   lanes 32..63 ("L2"): layer-2 row i, computing h2_{t-1}  at phase t
// Branchless: halves differ only in weight pointers (init) and LDS read bases.
// Per-lane weights = 64 VGPRs (vs 128 in R2) -> fits the 128-reg allocation
// spill-free -> 4 waves/SIMD. v_pk_fma_f32 halves FMA instruction count.
// Wave-synchronous: one s_waitcnt lgkmcnt(0) fence per phase (no __syncthreads,
// so the x global prefetch stays in flight across phases).
__global__ void __launch_bounds__(64) __attribute__((amdgpu_waves_per_eu(4)))
rnn_fused(
    const float* __restrict__ x,
    const float* __restrict__ Wih1, const float* __restrict__ Whh1,
    const float* __restrict__ bih1, const float* __restrict__ bhh1,
    const float* __restrict__ Wih2, const float* __restrict__ Whh2,
    const float* __restrict__ bih2, const float* __restrict__ bhh2,
    const float* __restrict__ Wfc, const float* __restrict__ bfc,
    float* __restrict__ out)
{
    __shared__ __align__(16) float xbuf[2][256];  // 2 chunks x 8 steps x 32
    __shared__ __align__(16) float hs[64];        // [0:32)=h1, [32:64)=h2

    const int lane = threadIdx.x;
    const int half = lane >> 5;
    const int i = lane & 31;
    const int b = blockIdx.x;

    // ---- per-half weight rows: W (input-side) and U (recurrent) ----
    const float* Wp = half ? Wih2 : Wih1;
    const float* Up = half ? Whh2 : Whh1;
    v2f wa[16], ub[16];
#pragma unroll
    for (int q = 0; q < 8; ++q) {
        float4 t0 = ((const float4*)(Wp + i * HH))[q];
        float4 t1 = ((const float4*)(Up + i * HH))[q];
        wa[2 * q] = flo(t0); wa[2 * q + 1] = fhi(t0);
        ub[2 * q] = flo(t1); ub[2 * q + 1] = fhi(t1);
    }
    const float* bip = half ? bih2 : bih1;
    const float* bhp = half ? bhh2 : bhh1;
    const float bias = bip[i] + bhp[i];

    const float4* xb4 = (const float4*)(x + (size_t)b * (TT * HH));

    // ---- LDS addressing: A-operand base differs per half ----
    char* xbase = (char*)&xbuf[0][0];
    const char* Abase = half ? (const char*)&hs[0] : (const char*)xbase;
    const unsigned maskA = half ? 0u : 0xFFFFFFFFu;       // L2 ignores x offsets
    const float4* Bp = (const float4*)(half ? &hs[32] : &hs[0]);

    // ---- prologue: zero hs, commit chunk 0, prefetch chunk 1 ----
    hs[lane] = 0.0f;
    float4 r = xb4[lane];                  // chunk 0 (t=0..7), 1 KB/wave
    ((float4*)xbase)[lane] = r;            // -> buf0
    r = xb4[64 + lane];                    // chunk 1 in flight
    asm volatile("s_waitcnt lgkmcnt(0)" ::: "memory");

    float last = 0.0f;

    auto phase = [&](unsigned xoff, bool zero_upper) {
        const float4* Ap = (const float4*)(Abase + (xoff & maskA));
        // A-term: L1: x_t ; L2: h1_{t-1}
        float4 a0 = Ap[0], a1 = Ap[1], a2 = Ap[2], a3 = Ap[3];
        v2f c0 = pk_mul(wa[0], flo(a0));
        v2f c1 = pk_mul(wa[1], fhi(a0));
        v2f c2 = pk_mul(wa[2], flo(a1));
        v2f c3 = pk_mul(wa[3], fhi(a1));
        float4 a4 = Ap[4], a5 = Ap[5], a6 = Ap[6], a7 = Ap[7];
        c0 = pk_fma(wa[4], flo(a2), c0);
        c1 = pk_fma(wa[5], fhi(a2), c1);
        c2 = pk_fma(wa[6], flo(a3), c2);
        c3 = pk_fma(wa[7], fhi(a3), c3);
        c0 = pk_fma(wa[8], flo(a4), c0);
        c1 = pk_fma(wa[9], fhi(a4), c1);
        c2 = pk_fma(wa[10], flo(a5), c2);
        c3 = pk_fma(wa[11], fhi(a5), c3);
        c0 = pk_fma(wa[12], flo(a6), c0);
        c1 = pk_fma(wa[13], fhi(a6), c1);
        c2 = pk_fma(wa[14], flo(a7), c2);
        c3 = pk_fma(wa[15], fhi(a7), c3);
        // B-term: L1: h1_{t-1} ; L2: h2_{t-2}
        float4 b0 = Bp[0], b1 = Bp[1], b2 = Bp[2], b3 = Bp[3];
        c0 = pk_fma(ub[0], flo(b0), c0);
        c1 = pk_fma(ub[1], fhi(b0), c1);
        c2 = pk_fma(ub[2], flo(b1), c2);
        c3 = pk_fma(ub[3], fhi(b1), c3);
        float4 b4 = Bp[4], b5 = Bp[5], b6 = Bp[6], b7 = Bp[7];
        c0 = pk_fma(ub[4], flo(b2), c0);
        c1 = pk_fma(ub[5], fhi(b2), c1);
        c2 = pk_fma(ub[6], flo(b3), c2);
        c3 = pk_fma(ub[7], fhi(b3), c3);
        c0 = pk_fma(ub[8], flo(b4), c0);
        c1 = pk_fma(ub[9], fhi(b4), c1);
        c2 = pk_fma(ub[10], flo(b5), c2);
        c3 = pk_fma(ub[11], fhi(b5), c3);
        c0 = pk_fma(ub[12], flo(b6), c0);
        c1 = pk_fma(ub[13], fhi(b6), c1);
        c2 = pk_fma(ub[14], flo(b7), c2);
        c3 = pk_fma(ub[15], fhi(b7), c3);
        v2f s = pk_add(pk_add(c0, c1), pk_add(c2, c3));
        float h = fast_tanh((s.x + s.y) + bias);
        if (zero_upper && half) h = 0.0f;   // phase 0: h2_{-1} must be 0
        hs[lane] = h;
        asm volatile("s_waitcnt lgkmcnt(0)" ::: "memory");
        return h;
    };

    // phase 0: t=0 for L1 (x chunk0 slot0); L2 output forced to 0
    last = phase(0u, true);

    // phases 1..512 : 64 chunk-iterations x 8 phases
#pragma unroll 2
    for (int c = 0; c < 64; ++c) {
        // commit chunk c+1 into buf[(c+1)&1] (regs loaded last iteration);
        // first read of it is phase s=7, 7 fences later — no race.
        ((float4*)(xbase + ((c + 1) & 1) * 1024))[lane] = r;
        // prefetch chunk c+2 (clamped; tail re-reads chunk 63 harmlessly)
        int cn = (c + 2 <= 63) ? (c + 2) : 63;
        r = xb4[cn * 64 + lane];
#pragma unroll
        for (int s = 0; s < 8; ++s) {
            // phase t = c*8+1+s : L1 reads slot (s+1)&7 of chunk c (s<7) or c+1 (s==7)
            unsigned slot = (unsigned)((s + 1) & 7);
            unsigned par = (s < 7) ? (unsigned)(c & 1) : (unsigned)((c + 1) & 1);
            last = phase(par * 1024u + slot * 128u, false);
        }
    }
    // (phase 512's L1 result is garbage-but-finite and never consumed)

    // ---- epilogue: out[b] = sum_i h2_511[i]*Wfc[i] + bfc ----
    float rr = last * Wfc[i];
    rr += __shfl_xor(rr, 1);
    rr += __shfl_xor(rr, 2);
    rr += __shfl_xor(rr, 4);
    rr += __shfl_xor(rr, 8);
    rr += __shfl_xor(rr, 16);
    if (lane == 32) out[b] = rr + bfc[0];
}

extern "C" void kernel_launch(void* const* d_in, const int* in_sizes, int n_in,
                              void* d_out, int out_size, void* d_ws, size_t ws_size,
                              hipStream_t stream) {
    const float* x    = (const float*)d_in[0];
    const float* Wih1 = (const float*)d_in[1];
    const float* Whh1 = (const float*)d_in[2];
    const float* bih1 = (const float*)d_in[3];
    const float* bhh1 = (const float*)d_in[4];
    const float* Wih2 = (const float*)d_in[5];
    const float* Whh2 = (const float*)d_in[6];
    const float* bih2 = (const float*)d_in[7];
    const float* bhh2 = (const float*)d_in[8];
    const float* Wfc  = (const float*)d_in[9];
    const float* bfc  = (const float*)d_in[10];
    float* out = (float*)d_out;

    rnn_fused<<<dim3(4096), dim3(64), 0, stream>>>(
        x, Wih1, Whh1, bih1, bhh1, Wih2, Whh2, bih2, bhh2, Wfc, bfc, out);
}

// Round 4
// 574.184 us; speedup vs baseline: 1.2486x; 1.2486x over previous
//
#include <hip/hip_runtime.h>

#define TT 512

__device__ __forceinline__ float fast_tanh(float z) {
    // tanh(z) = 1 - 2/(exp(2z)+1); exp2-based, ~1e-7 abs err (verified R1-R3)
    float e, r;
    float zz = z * 2.88539008177793f;  // 2*log2(e)
    asm("v_exp_f32 %0, %1" : "=v"(e) : "v"(zz));
    float d = e + 1.0f;
    asm("v_rcp_f32 %0, %1" : "=v"(r) : "v"(d));
    return __builtin_fmaf(-2.0f, r, 1.0f);
}

// 16-step systolic FMA chain via DPP row_ror:k (k=1..15; k=0 done by caller).
// acc += o[(r-k)&15] * w[k] per lane r (within its 16-lane DPP row).
// s_nop 1 guards the VALU-write -> DPP-read hazard (2 wait states); inline asm
// is opaque to the compiler's hazard recognizer, so we insert it ourselves.
__device__ __forceinline__ float chain16(float acc, float o, const float* w) {
    asm("s_nop 1\n\t"
        "v_fmac_f32 %0, %1, %2  row_ror:1  row_mask:0xf bank_mask:0xf\n\t"
        "v_fmac_f32 %0, %1, %3  row_ror:2  row_mask:0xf bank_mask:0xf\n\t"
        "v_fmac_f32 %0, %1, %4  row_ror:3  row_mask:0xf bank_mask:0xf\n\t"
        "v_fmac_f32 %0, %1, %5  row_ror:4  row_mask:0xf bank_mask:0xf\n\t"
        "v_fmac_f32 %0, %1, %6  row_ror:5  row_mask:0xf bank_mask:0xf\n\t"
        "v_fmac_f32 %0, %1, %7  row_ror:6  row_mask:0xf bank_mask:0xf\n\t"
        "v_fmac_f32 %0, %1, %8  row_ror:7  row_mask:0xf bank_mask:0xf\n\t"
        "v_fmac_f32 %0, %1, %9  row_ror:8  row_mask:0xf bank_mask:0xf\n\t"
        "v_fmac_f32 %0, %1, %10 row_ror:9  row_mask:0xf bank_mask:0xf\n\t"
        "v_fmac_f32 %0, %1, %11 row_ror:10 row_mask:0xf bank_mask:0xf\n\t"
        "v_fmac_f32 %0, %1, %12 row_ror:11 row_mask:0xf bank_mask:0xf\n\t"
        "v_fmac_f32 %0, %1, %13 row_ror:12 row_mask:0xf bank_mask:0xf\n\t"
        "v_fmac_f32 %0, %1, %14 row_ror:13 row_mask:0xf bank_mask:0xf\n\t"
        "v_fmac_f32 %0, %1, %15 row_ror:14 row_mask:0xf bank_mask:0xf\n\t"
        "v_fmac_f32 %0, %1, %16 row_ror:15 row_mask:0xf bank_mask:0xf"
        : "+v"(acc)
        : "v"(o), "v"(w[1]), "v"(w[2]), "v"(w[3]), "v"(w[4]), "v"(w[5]),
          "v"(w[6]), "v"(w[7]), "v"(w[8]), "v"(w[9]), "v"(w[10]), "v"(w[11]),
          "v"(w[12]), "v"(w[13]), "v"(w[14]), "v"(w[15]));
    return acc;
}

// One batch per 64-lane wave; 4 DPP-rows of 16 lanes:
//   row0: h1[0:16]  row1: h1[16:32]  row2: h2[0:16]  row3: h2[16:32]
// Lane holds 64 diagonal-packed weights (4 chains x 16). Layer 2 skewed one
// phase: phase t computes h1_t (rows 0-1) and h2_{t-1} (rows 2-3).
// Cross-row state handoff: 4 ds_bpermute with per-lane-constant indices
// (per-row source folds into (L&32)|(L&15)), + 2 cndmask for the x operand.
// Zero shared memory, zero broadcast LDS traffic (R2/R3's 327-440 us wall).
__global__ void __launch_bounds__(128) __attribute__((amdgpu_waves_per_eu(4, 4)))
rnn_dpp(
    const float* __restrict__ x,
    const float* __restrict__ Wih1, const float* __restrict__ Whh1,
    const float* __restrict__ bih1, const float* __restrict__ bhh1,
    const float* __restrict__ Wih2, const float* __restrict__ Whh2,
    const float* __restrict__ bih2, const float* __restrict__ bhh2,
    const float* __restrict__ Wfc, const float* __restrict__ bfc,
    float* __restrict__ out)
{
    const int L = threadIdx.x & 63;           // lane in wave
    const int b = blockIdx.x * 2 + (threadIdx.x >> 6);
    const int r = L & 15;                     // position within DPP row
    const bool lo32 = (L < 32);               // rows 0-1 = layer 1
    const int out_row = ((L >> 4) & 1) * 16 + r;

    // ---- diagonal-packed weights: w[k] = W[out_row][(r-k)&15 (+16)] ----
    const float* WA = lo32 ? Wih1 : Wih2;     // input-side matrix
    const float* WB = lo32 ? Whh1 : Whh2;     // recurrent matrix
    float w0[16], w1[16], w2[16], w3[16];
#pragma unroll
    for (int k = 0; k < 16; ++k) {
        int jlo = (r - k) & 15;
        w0[k] = WA[out_row * 32 + jlo];
        w1[k] = WA[out_row * 32 + 16 + jlo];
        w2[k] = WB[out_row * 32 + jlo];
        w3[k] = WB[out_row * 32 + 16 + jlo];
    }
    const float biasv = lo32 ? (bih1[out_row] + bhh1[out_row])
                             : (bih2[out_row] + bhh2[out_row]);

    // ---- bpermute indices (bytes), per-lane constants ----
    const int idx_plo = 4 * r;                        // h1p_lo for all rows
    const int idx_phi = 4 * (16 | r);                 // h1p_hi for all rows
    const int idx_s2  = 4 * ((L & 32) | r);           // rows01: h1p_lo; rows23: h2p_lo
    const int idx_s3  = 4 * ((L & 32) | 16 | r);      // rows01: h1p_hi; rows23: h2p_hi

    const float* xb = x + (size_t)b * (TT * 32);

    float myh = 0.0f;  // row0/1: h1[out_row]; row2/3: h2[out_row]

    auto phase = [&](float xlo, float xhi) {
        int mh = __float_as_int(myh);
        float Plo = __int_as_float(__builtin_amdgcn_ds_bpermute(idx_plo, mh));
        float Phi = __int_as_float(__builtin_amdgcn_ds_bpermute(idx_phi, mh));
        float S2  = __int_as_float(__builtin_amdgcn_ds_bpermute(idx_s2, mh));
        float S3  = __int_as_float(__builtin_amdgcn_ds_bpermute(idx_s3, mh));
        float S0 = lo32 ? xlo : Plo;   // rows01: x_t lo  | rows23: h1_{t-1} lo
        float S1 = lo32 ? xhi : Phi;   //        x_t hi  |         h1_{t-1} hi
        // k=0 terms (also distance-pad before the DPP blobs)
        float a0 = __builtin_fmaf(S0, w0[0], biasv);
        float a1 = S1 * w1[0];
        float a2 = S2 * w2[0];
        float a3 = S3 * w3[0];
        a0 = chain16(a0, S0, w0);
        a1 = chain16(a1, S1, w1);
        a2 = chain16(a2, S2, w2);
        a3 = chain16(a3, S3, w3);
        myh = fast_tanh((a0 + a1) + (a2 + a3));
    };

    // ---- x prefetch: 4-step chunks, double-buffered in 16 regs ----
    float xp[2][8];
#pragma unroll
    for (int s = 0; s < 4; ++s) {
        xp[0][2 * s]     = xb[s * 32 + r];
        xp[0][2 * s + 1] = xb[s * 32 + 16 + r];
    }

#pragma unroll 2
    for (int c = 0; c < 128; ++c) {
        // prefetch chunk c+1 into the other buffer (its old contents, chunk
        // c-1, were fully consumed last iteration)
        const int cp = (c + 1 < 128) ? c + 1 : 127;
#pragma unroll
        for (int s = 0; s < 4; ++s) {
            xp[(c + 1) & 1][2 * s]     = xb[(cp * 4 + s) * 32 + r];
            xp[(c + 1) & 1][2 * s + 1] = xb[(cp * 4 + s) * 32 + 16 + r];
        }
#pragma unroll
        for (int s = 0; s < 4; ++s) {
            phase(xp[c & 1][2 * s], xp[c & 1][2 * s + 1]);
            if (c == 0 && s == 0) {
                // h2_{-1} must be 0: rows 2-3 computed tanh(b2) garbage
                myh = lo32 ? myh : 0.0f;
            }
        }
    }
    // phase 512: rows 2-3 produce h2_511 (x operand is stale/ignored;
    // rows 0-1 produce finite garbage h1_512, never consumed)
    phase(xp[0][0], xp[0][1]);

    // ---- epilogue: out[b] = sum_i h2_511[i]*Wfc[i] + bfc ----
    float wfcv = Wfc[L & 31];
    float rr = lo32 ? 0.0f : myh * wfcv;
    rr += __shfl_xor(rr, 1);
    rr += __shfl_xor(rr, 2);
    rr += __shfl_xor(rr, 4);
    rr += __shfl_xor(rr, 8);
    rr += __shfl_xor(rr, 16);
    rr += __shfl_xor(rr, 32);
    if (L == 0) out[b] = rr + bfc[0];
}

extern "C" void kernel_launch(void* const* d_in, const int* in_sizes, int n_in,
                              void* d_out, int out_size, void* d_ws, size_t ws_size,
                              hipStream_t stream) {
    const float* x    = (const float*)d_in[0];
    const float* Wih1 = (const float*)d_in[1];
    const float* Whh1 = (const float*)d_in[2];
    const float* bih1 = (const float*)d_in[3];
    const float* bhh1 = (const float*)d_in[4];
    const float* Wih2 = (const float*)d_in[5];
    const float* Whh2 = (const float*)d_in[6];
    const float* bih2 = (const float*)d_in[7];
    const float* bhh2 = (const float*)d_in[8];
    const float* Wfc  = (const float*)d_in[9];
    const float* bfc  = (const float*)d_in[10];
    float* out = (float*)d_out;

    // 2048 blocks x 128 threads = 4096 waves, one batch each; 16 waves/CU
    rnn_dpp<<<dim3(2048), dim3(128), 0, stream>>>(
        x, Wih1, Whh1, bih1, bhh1, Wih2, Whh2, bih2, bhh2, Wfc, bfc, out);
}